// Round 3
// baseline (146.545 us; speedup 1.0000x reference)
//
#include <hip/hip_runtime.h>
#include <math.h>

// B=16384 rows, C=1000 cols, fp32 -> 16384 fp32. Inputs 131 MB; ~half is
// L3-resident from the harness re-poison (FETCH_SIZE ~65 MB/dispatch).
//
// R6: pipeline ACROSS rows. R3/R4/R5 all landed at 42-45 us despite wildly
// different shapes: every wave was phase-locked {load -> full-latency wait ->
// short compute -> exit}, so ~900cy of memory wait per row was always exposed
// (HBM 1.6 TB/s, VALU 43%, neither saturated = latency-bound). Now each block
// owns 4 consecutive rows and issues row k+1's loads BEFORE computing row k;
// steady-state waves consume data loaded one full row-compute earlier.
//
// Key detail: __syncthreads() would emit s_waitcnt vmcnt(0) before s_barrier
// and drain the prefetch every row. We use raw __builtin_amdgcn_s_barrier()
// with an explicit lgkmcnt(0) + "memory" asm fence: LDS cross-wave ordering
// is preserved, but the 2 prefetch loads stay in flight across barriers
// (compiler emits vmcnt(2) before the current payload is read, never 0).

constexpr int kC  = 1000;
constexpr int kNV = kC / 4;        // 250 float4 per row; threads 250..255 pad
constexpr int kRowsPerBlock = 4;

// Raw barrier: orders LDS (lgkmcnt(0)) and blocks compiler reordering of
// memory ops across it ("memory"), but does NOT drain vmcnt -> prefetch
// global loads survive.
__device__ __forceinline__ void block_barrier() {
    asm volatile("s_waitcnt lgkmcnt(0)" ::: "memory");
    __builtin_amdgcn_s_barrier();
    asm volatile("" ::: "memory");
}

__global__ __launch_bounds__(256, 4) void netsat_kernel(
    const float* __restrict__ y1, const float* __restrict__ y2,
    float* __restrict__ out, int nrows)
{
    const int tid  = threadIdx.x;
    const int lane = tid & 63;
    const int wave = tid >> 6;
    const int rb   = blockIdx.x * kRowsPerBlock;

    // Parity-alternated LDS so row k+1's writes can't race row k's readers.
    __shared__ float sm[2][4][4];      // [parity][wave] = {m1,m2,n1,n2}
    __shared__ float sbest[2][4];      // [parity][wave]

    const int vi = (tid < kNV) ? tid : (kNV - 1);   // clamped, branchless
    const float4 ninf4 = make_float4(-INFINITY, -INFINITY, -INFINITY, -INFINITY);

    // Double-buffered payload: cur row + next row, statically indexed
    // (loop fully unrolled -> k&1 is a compile-time constant).
    float4 pa[2], pb[2];
    {
        const int r0 = (rb < nrows) ? rb : (nrows - 1);
        const float4* r1 = reinterpret_cast<const float4*>(y1) + (size_t)r0 * kNV;
        const float4* r2 = reinterpret_cast<const float4*>(y2) + (size_t)r0 * kNV;
        pa[0] = r1[vi];
        pb[0] = r2[vi];
    }

#pragma unroll
    for (int k = 0; k < kRowsPerBlock; ++k) {
        const int cur = k & 1;
        const int nxt = cur ^ 1;

        // ---- prefetch row k+1 (stays in flight across both barriers) ----
        if (k + 1 < kRowsPerBlock) {
            int rn = rb + k + 1;
            if (rn >= nrows) rn = nrows - 1;
            const float4* r1 = reinterpret_cast<const float4*>(y1) + (size_t)rn * kNV;
            const float4* r2 = reinterpret_cast<const float4*>(y2) + (size_t)rn * kNV;
            pa[nxt] = r1[vi];
            pb[nxt] = r2[vi];
        }

        // ---- consume current row (compiler waits vmcnt(2) here, not 0) ----
        float4 a = pa[cur];
        float4 b = pb[cur];
        if (tid >= kNV) { a = ninf4; b = ninf4; }

        // ---- local top-2 over this thread's 4 elements, both inputs ----
        float m1 = -INFINITY, m2 = -INFINITY;
        float n1 = -INFINITY, n2 = -INFINITY;
        {
            const float* av = reinterpret_cast<const float*>(&a);
            const float* bv = reinterpret_cast<const float*>(&b);
#pragma unroll
            for (int e = 0; e < 4; ++e) {
                const float v = av[e];
                m2 = fmaxf(m2, fminf(m1, v)); m1 = fmaxf(m1, v);
                const float w = bv[e];
                n2 = fmaxf(n2, fminf(n1, w)); n1 = fmaxf(n1, w);
            }
        }

        // ---- wave butterfly merge of (top1, top2); m/n interleave (ILP) ----
#pragma unroll
        for (int off = 32; off > 0; off >>= 1) {
            const float o1 = __shfl_xor(m1, off, 64);
            const float o2 = __shfl_xor(m2, off, 64);
            const float p1 = __shfl_xor(n1, off, 64);
            const float p2 = __shfl_xor(n2, off, 64);
            m2 = fmaxf(fminf(m1, o1), fmaxf(m2, o2));
            m1 = fmaxf(m1, o1);
            n2 = fmaxf(fminf(n1, p1), fmaxf(n2, p2));
            n1 = fmaxf(n1, p1);
        }

        // ---- cross-wave merge via LDS; every thread merges all 4 waves ----
        if (lane == 0) {
            sm[cur][wave][0] = m1; sm[cur][wave][1] = m2;
            sm[cur][wave][2] = n1; sm[cur][wave][3] = n2;
        }
        block_barrier();

        float M1 = -INFINITY, M2 = -INFINITY, N1 = -INFINITY, N2 = -INFINITY;
#pragma unroll
        for (int w = 0; w < 4; ++w) {
            const float w1 = sm[cur][w][0], w2 = sm[cur][w][1];
            M2 = fmaxf(fminf(M1, w1), fmaxf(M2, w2));
            M1 = fmaxf(M1, w1);
            const float u1 = sm[cur][w][2], u2 = sm[cur][w][3];
            N2 = fmaxf(fminf(N1, u1), fmaxf(N2, u2));
            N1 = fmaxf(N1, u1);
        }

        // ---- pass 2 over REGISTER payload: max_j min(v-loo1, w-loo2) ----
        // loo(v) = (v==M1) ? M2 : M1 — tie-safe (duplicate max => M2==M1).
        float best = -INFINITY;
        {
            const float* av = reinterpret_cast<const float*>(&a);
            const float* bv = reinterpret_cast<const float*>(&b);
#pragma unroll
            for (int e = 0; e < 4; ++e) {
                const float v = av[e];
                const float w = bv[e];
                const float l1 = (v == M1) ? M2 : M1;
                const float l2 = (w == N1) ? N2 : N1;
                best = fmaxf(best, fminf(v - l1, w - l2));
            }
        }
#pragma unroll
        for (int off = 32; off > 0; off >>= 1)
            best = fmaxf(best, __shfl_xor(best, off, 64));

        if (lane == 0) sbest[cur][wave] = best;
        block_barrier();

        if (tid == 0) {
            const int rowk = rb + k;
            if (rowk < nrows) {
                out[rowk] = fmaxf(fmaxf(sbest[cur][0], sbest[cur][1]),
                                  fmaxf(sbest[cur][2], sbest[cur][3]));
            }
        }
    }
}

extern "C" void kernel_launch(void* const* d_in, const int* in_sizes, int n_in,
                              void* d_out, int out_size, void* d_ws, size_t ws_size,
                              hipStream_t stream) {
    const float* y1 = (const float*)d_in[0];
    const float* y2 = (const float*)d_in[1];
    float* out = (float*)d_out;
    const int nrows = out_size;  // 16384
    const int blocks = (nrows + kRowsPerBlock - 1) / kRowsPerBlock;  // 4096
    netsat_kernel<<<blocks, 256, 0, stream>>>(y1, y2, out, nrows);
}

// Round 4
// 141.335 us; speedup vs baseline: 1.0369x; 1.0369x over previous
//
#include <hip/hip_runtime.h>
#include <math.h>

// B=16384 rows, C=1000 cols, fp32 -> 16384 fp32. Inputs 131 MB, fully
// L3-resident (FETCH_SIZE ~65 MB/dispatch after harness re-poison).
//
// R7: persistent wave-per-row, two streaming passes, ZERO barriers/LDS.
// Accumulated evidence from R1-R6 (all 42-51 us):
//  (a) block-per-row spends ~87% of VALU on butterfly/LDS-merge overhead
//      (200 overhead instrs per 256 elements); wave-per-row amortizes the
//      same overhead over 1000 elements.
//  (b) short-lived blocks are capped at ~5/CU by workgroup dispatch rate
//      (~390 wg/us observed vs ~620 needed); 2048 persistent blocks
//      (8/CU, 100% occupancy) are dispatched once.
//  (c) register-resident row payloads lose to the allocator every time
//      (VGPR stuck at 20-28); instead pass 2 RE-READS the row, which hits
//      L1/L2/L3 (everything fits the 256 MiB Infinity Cache) — no extra
//      HBM traffic, latency covered by 8 phase-staggered waves/SIMD with
//      no barrier anywhere to phase-lock them.

constexpr int kC  = 1000;
constexpr int kNV = kC / 4;        // 250 float4 per row
constexpr int kBlocks = 2048;      // 8 blocks/CU * 256 CU — persistent

__device__ __forceinline__ void top2_push(float v, float& t1, float& t2) {
    t2 = fmaxf(t2, fminf(t1, v));
    t1 = fmaxf(t1, v);
}

__global__ __launch_bounds__(256, 8) void netsat_kernel(
    const float* __restrict__ y1, const float* __restrict__ y2,
    float* __restrict__ out, int nrows)
{
    const int lane  = threadIdx.x & 63;
    const int wid   = blockIdx.x * 4 + (threadIdx.x >> 6);
    const int nwave = kBlocks * 4;                 // 8192 waves -> 2 rows/wave

    // Chunk 3 is index-clamped; lanes 58..63 would duplicate float4 #249,
    // which is only safe in pass 2 (max of duplicates). Pass 1 (top-2)
    // must see each element once -> mask dup lanes to -inf.
    const int  i3  = (lane + 192 < kNV) ? (lane + 192) : (kNV - 1);
    const bool dup = (lane + 192) >= kNV;
    const float4 ninf4 = make_float4(-INFINITY, -INFINITY, -INFINITY, -INFINITY);

    for (int row = wid; row < nrows; row += nwave) {
        const float4* r1 = reinterpret_cast<const float4*>(y1) + (size_t)row * kNV;
        const float4* r2 = reinterpret_cast<const float4*>(y2) + (size_t)row * kNV;

        // ---------------- pass 1: per-input top-2 over the row ----------------
        float m1 = -INFINITY, m2 = -INFINITY;   // y1
        float n1 = -INFINITY, n2 = -INFINITY;   // y2
        {
            float4 A[4], B[4];
            A[0] = r1[lane];       B[0] = r2[lane];
            A[1] = r1[lane + 64];  B[1] = r2[lane + 64];
            A[2] = r1[lane + 128]; B[2] = r2[lane + 128];
            A[3] = r1[i3];         B[3] = r2[i3];
            if (dup) { A[3] = ninf4; B[3] = ninf4; }
#pragma unroll
            for (int c = 0; c < 4; ++c) {
                const float* av = reinterpret_cast<const float*>(&A[c]);
                const float* bv = reinterpret_cast<const float*>(&B[c]);
#pragma unroll
                for (int e = 0; e < 4; ++e) {
                    top2_push(av[e], m1, m2);
                    top2_push(bv[e], n1, n2);
                }
            }
        }

        // wave butterfly merge of (top1, top2); m/n chains interleave (ILP)
#pragma unroll
        for (int off = 32; off > 0; off >>= 1) {
            const float o1 = __shfl_xor(m1, off, 64);
            const float o2 = __shfl_xor(m2, off, 64);
            const float p1 = __shfl_xor(n1, off, 64);
            const float p2 = __shfl_xor(n2, off, 64);
            m2 = fmaxf(fminf(m1, o1), fmaxf(m2, o2));
            m1 = fmaxf(m1, o1);
            n2 = fmaxf(fminf(n1, p1), fmaxf(n2, p2));
            n1 = fmaxf(n1, p1);
        }
        // every lane now holds the row-wide (m1,m2,n1,n2)

        // ---------------- pass 2: re-read row (L1/L2/L3 hit) ----------------
        // loo(v) = (v==m1) ? m2 : m1 — tie-safe (duplicated max => m2==m1).
        // Dup lanes recompute element 249's contribution — harmless for max.
        float best = -INFINITY;
        {
            float4 A[4], B[4];
            A[0] = r1[lane];       B[0] = r2[lane];
            A[1] = r1[lane + 64];  B[1] = r2[lane + 64];
            A[2] = r1[lane + 128]; B[2] = r2[lane + 128];
            A[3] = r1[i3];         B[3] = r2[i3];
#pragma unroll
            for (int c = 0; c < 4; ++c) {
                const float* av = reinterpret_cast<const float*>(&A[c]);
                const float* bv = reinterpret_cast<const float*>(&B[c]);
#pragma unroll
                for (int e = 0; e < 4; ++e) {
                    const float v = av[e];
                    const float w = bv[e];
                    const float l1 = (v == m1) ? m2 : m1;
                    const float l2 = (w == n1) ? n2 : n1;
                    best = fmaxf(best, fminf(v - l1, w - l2));
                }
            }
        }
#pragma unroll
        for (int off = 32; off > 0; off >>= 1)
            best = fmaxf(best, __shfl_xor(best, off, 64));

        if (lane == 0) out[row] = best;
    }
}

extern "C" void kernel_launch(void* const* d_in, const int* in_sizes, int n_in,
                              void* d_out, int out_size, void* d_ws, size_t ws_size,
                              hipStream_t stream) {
    const float* y1 = (const float*)d_in[0];
    const float* y2 = (const float*)d_in[1];
    float* out = (float*)d_out;
    const int nrows = out_size;  // 16384
    netsat_kernel<<<kBlocks, 256, 0, stream>>>(y1, y2, out, nrows);
}